// Round 4
// baseline (71.824 us; speedup 1.0000x reference)
//
#include <hip/hip_runtime.h>
#include <hip/hip_bf16.h>
#include <math.h>

// ---------------------------------------------------------------------------
// RnCLoss, fully fused single kernel + counter-reset memset node.
//   loss = -1/(n(n-1)) * sum_{i,k!=i} [ logit(i,k) - log denom(i,k) ]
//   logit(i,j) = 0.5*sqrt(max(2 - 2*G_ij*rsqrt(G_ii*G_jj), 0)), G = F F^T
//   denom(i,k) = sum_{j!=i, |l_i-l_j| >= |l_i-l_k|} exp(logit(i,j))
//
// Phases (one 512-block kernel, __launch_bounds__(256,2) guarantees all
// blocks co-resident -> grid spin-barrier is safe):
//   0: block b computes norms[b] = ||f_b||^2
//   1: waves 0,1 of block b compute 16x16 MFMA fragments 2b, 2b+1 of G
//      (operands straight from global/L2, fp32->bf16 in regs; G symmetric
//       so any frag-layout transpose is harmless)
//   -- grid barrier (agent-scope atomics; cross-XCD safe) --
//   2: block b computes row-b masked-denominator loss; last block reduces.
// Counters live in ws[0..255], zeroed each call by a captured memset node.
// ---------------------------------------------------------------------------

typedef __attribute__((ext_vector_type(8))) short short8;
typedef __attribute__((ext_vector_type(4))) float f32x4;

static __device__ __forceinline__ unsigned short bf16_bits(float f) {
    __hip_bfloat16 h = __float2bfloat16(f);  // RNE
    return *reinterpret_cast<unsigned short*>(&h);
}

static __device__ __forceinline__ short8 to_bf16x8(float4 a, float4 b) {
    short8 r;
    r[0] = (short)bf16_bits(a.x); r[1] = (short)bf16_bits(a.y);
    r[2] = (short)bf16_bits(a.z); r[3] = (short)bf16_bits(a.w);
    r[4] = (short)bf16_bits(b.x); r[5] = (short)bf16_bits(b.y);
    r[6] = (short)bf16_bits(b.z); r[7] = (short)bf16_bits(b.w);
    return r;
}

__global__ __launch_bounds__(256, 2) void k_fused(
        const float* __restrict__ F, const float* __restrict__ labels,
        float* __restrict__ G, float* __restrict__ norms,
        float* __restrict__ row_sums,
        unsigned* __restrict__ ctr_bar, unsigned* __restrict__ ctr_fin,
        float* __restrict__ out, int n, int d) {
    const int b    = blockIdx.x;
    const int t    = threadIdx.x;
    const int lane = t & 63;
    const int w    = t >> 6;

    __shared__ float2 lde[512];
    __shared__ float  lab_s[512];
    __shared__ float  ndg_s[512];
    __shared__ float  red[4];
    __shared__ int    flag_s;

    // ---- phase 0: norms[b] = ||f_b||^2 (fixed-order within lanes) ----
    {
        const float* fr = F + (size_t)b * d;
        float s = 0.f;
        for (int c = t * 2; c < d; c += 512) {
            float2 v = *(const float2*)&fr[c];
            s += v.x * v.x + v.y * v.y;
        }
        #pragma unroll
        for (int off = 32; off > 0; off >>= 1) s += __shfl_down(s, off);
        if (lane == 0) red[w] = s;
        __syncthreads();
        if (t == 0) {
            float tot = red[0] + red[1] + red[2] + red[3];
            __hip_atomic_store(&norms[b], tot, __ATOMIC_RELAXED,
                               __HIP_MEMORY_SCOPE_AGENT);
        }
    }

    // ---- phase 1: MFMA fragments of G, waves 0 and 1 only ----
    {
        const int nf = n >> 4;          // fragment grid dim (32)
        const int f  = b * 2 + w;       // fragment id
        if (w < 2 && f < nf * nf) {
            const int fi = f / nf;
            const int fj = f % nf;
            const float* Arow = F + (size_t)(fi * 16 + (lane & 15)) * d;
            const float* Brow = F + (size_t)(fj * 16 + (lane & 15)) * d;
            const int kb = (lane >> 4) << 3;   // 0,8,16,24

            f32x4 acc = {};
            #pragma unroll 2
            for (int k0 = 0; k0 < d; k0 += 32) {
                float4 a0 = *(const float4*)&Arow[k0 + kb];
                float4 a1 = *(const float4*)&Arow[k0 + kb + 4];
                float4 b0 = *(const float4*)&Brow[k0 + kb];
                float4 b1 = *(const float4*)&Brow[k0 + kb + 4];
                short8 af = to_bf16x8(a0, a1);
                short8 bf = to_bf16x8(b0, b1);
                acc = __builtin_amdgcn_mfma_f32_16x16x32_bf16(af, bf, acc, 0, 0, 0);
            }
            // C/D: col = lane&15, row = (lane>>4)*4 + r   (G symmetric)
            const int orow = fi * 16 + ((lane >> 4) << 2);
            const int ocol = fj * 16 + (lane & 15);
            #pragma unroll
            for (int r = 0; r < 4; ++r)
                G[(size_t)(orow + r) * n + ocol] = acc[r];
        }
    }

    // ---- grid barrier ----
    __syncthreads();   // all waves' stores drained (vmcnt0) before release
    if (t == 0) {
        __hip_atomic_fetch_add(ctr_bar, 1u, __ATOMIC_ACQ_REL,
                               __HIP_MEMORY_SCOPE_AGENT);
        while (__hip_atomic_load(ctr_bar, __ATOMIC_ACQUIRE,
                                 __HIP_MEMORY_SCOPE_AGENT) < (unsigned)gridDim.x) {
            __builtin_amdgcn_s_sleep(1);
        }
    }
    __syncthreads();

    // ---- phase 2: loss for row i = b ----
    const int i = b;
    for (int j = t; j < n; j += 256) {
        lab_s[j] = labels[j];
        ndg_s[j] = norms[j];
    }
    __syncthreads();

    float li = lab_s[i];
    float di = ndg_s[i];
    const float* Grow = G + (size_t)i * n;

    float lgt[2], ldk[2];
    int kj[2];
    #pragma unroll
    for (int q = 0; q < 2; ++q) {
        int j = t + q * 256;
        kj[q] = j;
        float g  = Grow[j] * rsqrtf(di * ndg_s[j]);
        float sq = fmaxf(2.f - 2.f * g, 0.f);
        float lg = 0.5f * sqrtf(sq);
        float e  = (j == i) ? 0.f : expf(lg);
        float ld = fabsf(li - lab_s[j]);
        lde[j] = make_float2(ld, e);
        lgt[q] = lg;
        ldk[q] = ld;
    }
    __syncthreads();

    float s0 = 0.f, s1 = 0.f;
    #pragma unroll 8
    for (int j = 0; j < n; ++j) {
        float2 p = lde[j];  // wave-uniform address -> LDS broadcast
        s0 += (p.x >= ldk[0]) ? p.y : 0.f;
        s1 += (p.x >= ldk[1]) ? p.y : 0.f;
    }

    float acc = 0.f;
    if (kj[0] != i) acc += lgt[0] - logf(s0);
    if (kj[1] != i) acc += lgt[1] - logf(s1);

    #pragma unroll
    for (int off = 32; off > 0; off >>= 1) acc += __shfl_down(acc, off);
    if (lane == 0) red[w] = acc;
    __syncthreads();
    if (t == 0) {
        float rs = red[0] + red[1] + red[2] + red[3];
        __hip_atomic_store(&row_sums[i], rs, __ATOMIC_RELEASE,
                           __HIP_MEMORY_SCOPE_AGENT);
        unsigned prev = __hip_atomic_fetch_add(ctr_fin, 1u, __ATOMIC_ACQ_REL,
                                               __HIP_MEMORY_SCOPE_AGENT);
        flag_s = (prev == (unsigned)(gridDim.x - 1));
    }
    __syncthreads();

    if (flag_s) {
        // deterministic fixed-order final reduction
        float s = 0.f;
        for (int r = t; r < n; r += 256)
            s += __hip_atomic_load(&row_sums[r], __ATOMIC_ACQUIRE,
                                   __HIP_MEMORY_SCOPE_AGENT);
        #pragma unroll
        for (int off = 32; off > 0; off >>= 1) s += __shfl_down(s, off);
        if (lane == 0) red[w] = s;
        __syncthreads();
        if (t == 0) {
            float tot = red[0] + red[1] + red[2] + red[3];
            out[0] = -tot / ((float)n * ((float)n - 1.0f));
        }
    }
}

extern "C" void kernel_launch(void* const* d_in, const int* in_sizes, int n_in,
                              void* d_out, int out_size, void* d_ws, size_t ws_size,
                              hipStream_t stream) {
    const float* F      = (const float*)d_in[0];
    const float* labels = (const float*)d_in[1];
    int n = in_sizes[1];            // 512
    int d = in_sizes[0] / n;        // 512
    float* out = (float*)d_out;

    char* ws = (char*)d_ws;
    unsigned* ctr_bar = (unsigned*)(ws + 0);
    unsigned* ctr_fin = (unsigned*)(ws + 64);
    float* row_sums   = (float*)(ws + 4096);            // n floats
    float* norms      = (float*)(ws + 8192);            // n floats
    float* G          = (float*)(ws + 16384);           // n*n floats

    // zero the barrier counters every call (ws is poisoned 0xAA pre-timing);
    // async memset is graph-capturable (harness itself uses it).
    hipMemsetAsync(ws, 0, 256, stream);
    k_fused<<<n, 256, 0, stream>>>(F, labels, G, norms, row_sums,
                                   ctr_bar, ctr_fin, out, n, d);
}

// Round 5
// 46.928 us; speedup vs baseline: 1.5305x; 1.5305x over previous
//
#include <hip/hip_runtime.h>
#include <hip/hip_bf16.h>
#include <math.h>

// ---------------------------------------------------------------------------
// RnCLoss: loss = -1/(n(n-1)) * sum_{i,k!=i} [ logit(i,k) - log denom(i,k) ]
//   logit(i,j) = 0.5*sqrt(max(2 - 2*G_ij*rsqrt(G_ii*G_jj), 0)), G = F F^T
//   denom(i,k) = sum_{j!=i, |l_i-l_j| >= |l_i-l_k|} exp(logit(i,j))
//
// 3 kernels:
//  1) prep:  F (fp32) -> Fb (bf16, MFMA-fragment-swizzled tiles) + row norms
//            + finalize-counter reset.  Gather cost paid ONCE here so the
//            GEMM's loads are perfectly coalesced.
//  2) gemm:  1024 waves, one 16x16 frag each; operands straight from L2 via
//            coalesced 1KB loads; K fully unrolled (32 loads in flight).
//  3) loss:  per-row masked-denominator loss, 128 thr x 4 k/thread
//            (balances LDS-broadcast pipe vs VALU), last-block final reduce.
//
// Fb layout: tile t=(r,s), r=rowblock in [0,32), s=ksub in [0,16).
//   ushort index: (r*16+s)*512 + lane*8 + e
//   element:      F[r*16 + (lane&15)][s*32 + (lane>>4)*8 + e]
// A k-permutation is dot-product-invariant; G symmetric -> frag transpose ok.
// ---------------------------------------------------------------------------

typedef __attribute__((ext_vector_type(8))) short short8;
typedef __attribute__((ext_vector_type(4))) float f32x4;

static __device__ __forceinline__ unsigned short bf16_bits(float f) {
    __hip_bfloat16 h = __float2bfloat16(f);  // RNE
    return *reinterpret_cast<unsigned short*>(&h);
}

// Kernel 1: one wave per block; block b handles swizzle-tile b=(r*16+s) and
// the norm of row b.
__global__ __launch_bounds__(64) void k_prep(const float* __restrict__ F,
                                             unsigned short* __restrict__ Fb,
                                             float* __restrict__ norms,
                                             unsigned* __restrict__ ctr,
                                             int n, int d) {
    const int b = blockIdx.x;
    const int l = threadIdx.x;
    if (b == 0 && l == 0) *ctr = 0u;

    // --- swizzle tile b: gather 16 rows x 32 k, emit bf16 frag layout ---
    {
        const int r = b >> 4, s = b & 15;
        const float* src = &F[(size_t)(r * 16 + (l & 15)) * d + s * 32 + ((l >> 4) << 3)];
        float4 a0 = *(const float4*)src;
        float4 a1 = *(const float4*)(src + 4);
        short8 v;
        v[0] = (short)bf16_bits(a0.x); v[1] = (short)bf16_bits(a0.y);
        v[2] = (short)bf16_bits(a0.z); v[3] = (short)bf16_bits(a0.w);
        v[4] = (short)bf16_bits(a1.x); v[5] = (short)bf16_bits(a1.y);
        v[6] = (short)bf16_bits(a1.z); v[7] = (short)bf16_bits(a1.w);
        *(short8*)&Fb[(size_t)b * 512 + l * 8] = v;  // coalesced 1KB store
    }

    // --- norm of row b (fixed-order reduce -> deterministic) ---
    {
        const float* fr = F + (size_t)b * d;
        float s = 0.f;
        for (int c = l * 8; c < d; c += 512) {
            float4 x = *(const float4*)&fr[c];
            float4 y = *(const float4*)&fr[c + 4];
            s += x.x * x.x + x.y * x.y + x.z * x.z + x.w * x.w
               + y.x * y.x + y.y * y.y + y.z * y.z + y.w * y.w;
        }
        #pragma unroll
        for (int off = 32; off > 0; off >>= 1) s += __shfl_down(s, off);
        if (l == 0) norms[b] = s;
    }
}

// Kernel 2: wave w of block b computes fragment f = b*4+w of the 32x32 frag
// grid. All loads coalesced 16B/lane from the swizzled Fb (L2-resident).
__global__ __launch_bounds__(256) void k_gemm(const unsigned short* __restrict__ Fb,
                                              float* __restrict__ G, int n) {
    const int l = threadIdx.x & 63;
    const int w = threadIdx.x >> 6;
    const int f = blockIdx.x * 4 + w;
    const int fi = f >> 5;
    const int fj = f & 31;

    const short8* A = (const short8*)&Fb[(size_t)fi * 16 * 512 + l * 8];
    const short8* B = (const short8*)&Fb[(size_t)fj * 16 * 512 + l * 8];

    f32x4 acc = {};
    #pragma unroll
    for (int s = 0; s < 16; ++s) {
        short8 av = A[s * 64];   // tile (fi,s): +512 ushorts = +64 short8
        short8 bv = B[s * 64];
        acc = __builtin_amdgcn_mfma_f32_16x16x32_bf16(av, bv, acc, 0, 0, 0);
    }

    // C/D mapping: col = lane&15, row = (lane>>4)*4 + r  (G symmetric)
    const int orow = fi * 16 + ((l >> 4) << 2);
    const int ocol = fj * 16 + (l & 15);
    #pragma unroll
    for (int r = 0; r < 4; ++r)
        G[(size_t)(orow + r) * n + ocol] = acc[r];
}

// Kernel 3: one block (128 thr, 2 waves) per row i; 4 k-values per thread.
__global__ __launch_bounds__(128) void k_loss(const float* __restrict__ labels,
                                              const float* __restrict__ G,
                                              const float* __restrict__ norms,
                                              float* __restrict__ row_sums,
                                              unsigned* __restrict__ ctr,
                                              float* __restrict__ out, int n) {
    const int i = blockIdx.x;
    const int t = threadIdx.x;
    __shared__ float2 lde[512];
    __shared__ float  lab_s[512];
    __shared__ float  nrm_s[512];
    __shared__ float  red[2];
    __shared__ int    flag_s;

    for (int j = t; j < n; j += 128) {
        lab_s[j] = labels[j];
        nrm_s[j] = norms[j];
    }
    __syncthreads();

    const float li = lab_s[i];
    const float di = nrm_s[i];
    const float* Grow = G + (size_t)i * n;

    float lgt[4], ldk[4];
    #pragma unroll
    for (int q = 0; q < 4; ++q) {
        int j = t + q * 128;
        float g  = Grow[j] * rsqrtf(di * nrm_s[j]);
        float sq = fmaxf(2.f - 2.f * g, 0.f);
        float lg = 0.5f * sqrtf(sq);
        float e  = (j == i) ? 0.f : expf(lg);
        float ld = fabsf(li - lab_s[j]);
        lde[j] = make_float2(ld, e);
        lgt[q] = lg;
        ldk[q] = ld;
    }
    __syncthreads();

    float s0 = 0.f, s1 = 0.f, s2 = 0.f, s3 = 0.f;
    #pragma unroll 8
    for (int j = 0; j < n; ++j) {
        float2 p = lde[j];  // wave-uniform address -> LDS broadcast
        s0 += (p.x >= ldk[0]) ? p.y : 0.f;
        s1 += (p.x >= ldk[1]) ? p.y : 0.f;
        s2 += (p.x >= ldk[2]) ? p.y : 0.f;
        s3 += (p.x >= ldk[3]) ? p.y : 0.f;
    }
    float sv[4] = {s0, s1, s2, s3};

    float acc = 0.f;
    #pragma unroll
    for (int q = 0; q < 4; ++q)
        if (t + q * 128 != i) acc += lgt[q] - logf(sv[q]);

    #pragma unroll
    for (int off = 32; off > 0; off >>= 1) acc += __shfl_down(acc, off);
    const int lane = t & 63, wid = t >> 6;
    if (lane == 0) red[wid] = acc;
    __syncthreads();
    if (t == 0) {
        float rs = red[0] + red[1];
        __hip_atomic_store(&row_sums[i], rs, __ATOMIC_RELEASE,
                           __HIP_MEMORY_SCOPE_AGENT);
        unsigned prev = __hip_atomic_fetch_add(ctr, 1u, __ATOMIC_ACQ_REL,
                                               __HIP_MEMORY_SCOPE_AGENT);
        flag_s = (prev == (unsigned)(gridDim.x - 1));
    }
    __syncthreads();

    if (flag_s) {
        // deterministic fixed-order final reduction
        float s = 0.f;
        for (int r = t; r < n; r += 128)
            s += __hip_atomic_load(&row_sums[r], __ATOMIC_ACQUIRE,
                                   __HIP_MEMORY_SCOPE_AGENT);
        #pragma unroll
        for (int off = 32; off > 0; off >>= 1) s += __shfl_down(s, off);
        if (lane == 0) red[wid] = s;
        __syncthreads();
        if (t == 0) out[0] = -(red[0] + red[1]) / ((float)n * ((float)n - 1.0f));
    }
}

extern "C" void kernel_launch(void* const* d_in, const int* in_sizes, int n_in,
                              void* d_out, int out_size, void* d_ws, size_t ws_size,
                              hipStream_t stream) {
    const float* F      = (const float*)d_in[0];
    const float* labels = (const float*)d_in[1];
    int n = in_sizes[1];            // 512
    int d = in_sizes[0] / n;        // 512
    float* out = (float*)d_out;

    char* ws = (char*)d_ws;
    unsigned* ctr       = (unsigned*)ws;                    // 4 B
    float* row_sums     = (float*)(ws + 4096);              // n floats
    float* norms        = (float*)(ws + 8192);              // n floats
    unsigned short* Fb  = (unsigned short*)(ws + 16384);    // n*d bf16 (512 KB)
    float* G            = (float*)(ws + 16384 + (size_t)n * d * 2);  // n*n fp32

    int ntiles = (n / 16) * (d / 32);        // 512
    int nfrag  = (n / 16) * (n / 16);        // 1024

    k_prep<<<ntiles, 64, 0, stream>>>(F, Fb, norms, ctr, n, d);
    k_gemm<<<nfrag / 4, 256, 0, stream>>>(Fb, G, n);
    k_loss<<<n, 128, 0, stream>>>(labels, G, norms, row_sums, ctr, out, n);
}